// Round 5
// baseline (415.825 us; speedup 1.0000x reference)
//
#include <hip/hip_runtime.h>
#include <math.h>

#define N_BINSK  500
#define N_SPL    1499
#define N_CELLSK 128
#define N_GOI    300
#define N_HIDK   32
#define N_LATK   64
#define N_FRAGK  50000
#define N_PAIR   (N_CELLSK * N_GOI)
#define WIN_A_F  (-10000.0f)
#define AB_F     (20000.0f)

#define CELLS_PB 8
#define N_TILES  (N_CELLSK / CELLS_PB)    // 16
#define CSTRIDE  1509   // per-cell floats in P: PW@0 (501 used), PH@504 (501), UD@1008 (499)

// ---- workspace layout (bytes) ----
#define WS_HIST  0                                   // int[38400]          @0
#define WS_ACC   (N_PAIR * 4)                        // double[192]         @153600
#define WS_NACT  (WS_ACC + 192 * 8)                  // int[300]            @155136
#define WS_H     (WS_NACT + 300 * 4)                 // float[128*32]       @156336 (16B aligned)
#define WS_OFF   (WS_H + N_CELLSK * N_HIDK * 4)      // int[38401]          @172720
#define WS_CUR   (WS_OFF + (N_PAIR + 1) * 4)         // int[38400]          @326324
#define WS_SORT  (WS_CUR + N_PAIR * 4)               // int[50000]          @479924
#define WS_ACT   (WS_SORT + N_FRAGK * 4)             // int[300*128]        @679924
#define WS_ZERO  (WS_H)                              // memset hist+acc+nact

#define HIST_BLOCKS 196   // 196*256 = 50176 >= 50000; block 196 runs the MLP

// ---------------------------------------------------------------- MLP (block HIST_BLOCKS) + histogram
__global__ __launch_bounds__(256) void mlp_hist_kernel(
    const float* __restrict__ latent, const float* __restrict__ W1, const float* __restrict__ b1,
    const float* __restrict__ g1, const float* __restrict__ be1,
    const float* __restrict__ W2, const float* __restrict__ b2,
    const float* __restrict__ g2, const float* __restrict__ be2,
    float* __restrict__ h_out, const int* __restrict__ lcx, int* __restrict__ hist)
{
    if (blockIdx.x < HIST_BLOCKS) {
        const int f = blockIdx.x * 256 + threadIdx.x;
        if (f < N_FRAGK) atomicAdd(&hist[lcx[f]], 1);
        return;
    }
    __shared__ float A[N_CELLSK][N_HIDK + 1];
    __shared__ float mean_s[N_HIDK], rstd_s[N_HIDK];
    const int c = threadIdx.x;
    const bool act = (c < N_CELLSK);

    float x[N_LATK];
    if (act) {
        #pragma unroll
        for (int i = 0; i < N_LATK; ++i) x[i] = latent[c * N_LATK + i];
        for (int j = 0; j < N_HIDK; ++j) {
            float a = b1[j];
            #pragma unroll
            for (int i = 0; i < N_LATK; ++i) a = fmaf(x[i], W1[i * N_HIDK + j], a);
            A[c][j] = fmaxf(a, 0.0f);
        }
    }
    __syncthreads();
    if (c < N_HIDK) {
        float m = 0.f;
        for (int i = 0; i < N_CELLSK; ++i) m += A[i][c];
        m *= (1.0f / N_CELLSK);
        float v = 0.f;
        for (int i = 0; i < N_CELLSK; ++i) { float d = A[i][c] - m; v += d * d; }
        v *= (1.0f / N_CELLSK);
        mean_s[c] = m;
        rstd_s[c] = rsqrtf(v + 1e-5f);
    }
    __syncthreads();
    float hb[N_HIDK];
    if (act) {
        #pragma unroll
        for (int j = 0; j < N_HIDK; ++j)
            hb[j] = (A[c][j] - mean_s[j]) * rstd_s[j] * g1[j] + be1[j];
    }
    __syncthreads();
    if (act) {
        for (int j = 0; j < N_HIDK; ++j) {
            float a = b2[j];
            #pragma unroll
            for (int i = 0; i < N_HIDK; ++i) a = fmaf(hb[i], W2[i * N_HIDK + j], a);
            A[c][j] = fmaxf(a, 0.0f);
        }
    }
    __syncthreads();
    if (c < N_HIDK) {
        float m = 0.f;
        for (int i = 0; i < N_CELLSK; ++i) m += A[i][c];
        m *= (1.0f / N_CELLSK);
        float v = 0.f;
        for (int i = 0; i < N_CELLSK; ++i) { float d = A[i][c] - m; v += d * d; }
        v *= (1.0f / N_CELLSK);
        mean_s[c] = m;
        rstd_s[c] = rsqrtf(v + 1e-5f);
    }
    __syncthreads();
    if (act) {
        #pragma unroll
        for (int j = 0; j < N_HIDK; ++j)
            h_out[c * N_HIDK + j] = (A[c][j] - mean_s[j]) * rstd_s[j] * g2[j] + be2[j];
    }
}

// ---------------------------------------------------------------- exclusive scan of hist -> off, cur; also active-cell lists
__global__ __launch_bounds__(1024) void scan_kernel(const int* __restrict__ hist,
                                                    int* __restrict__ off,
                                                    int* __restrict__ cur,
                                                    int* __restrict__ nact,
                                                    int* __restrict__ act_list)
{
    __shared__ int wsum[16];
    const int t = threadIdx.x, lane = t & 63, w = t >> 6;
    const int base = t * 38;
    int loc[38];
    int run = 0;
    #pragma unroll
    for (int k = 0; k < 38; ++k) {
        const int i = base + k;
        const int v = (i < N_PAIR) ? hist[i] : 0;
        loc[k] = run; run += v;
        if (v > 0) {
            const int gl = i % N_GOI;
            const int cell = i / N_GOI;
            const int pos = atomicAdd(&nact[gl], 1);
            act_list[gl * N_CELLSK + pos] = cell;
        }
    }
    int s = run;
    #pragma unroll
    for (int o = 1; o < 64; o <<= 1) {
        int tt = __shfl_up(s, o);
        if (lane >= o) s += tt;
    }
    if (lane == 63) wsum[w] = s;
    __syncthreads();
    if (t == 0) {
        int r = 0;
        #pragma unroll
        for (int j = 0; j < 16; ++j) { const int x = wsum[j]; wsum[j] = r; r += x; }
    }
    __syncthreads();
    const int ex = wsum[w] + (s - run);
    #pragma unroll
    for (int k = 0; k < 38; ++k) {
        const int i = base + k;
        if (i < N_PAIR) { off[i] = ex + loc[k]; cur[i] = ex + loc[k]; }
    }
    if (t == 1023) off[N_PAIR] = ex + run;
}

// ---------------------------------------------------------------- scatter fragments sorted by pair
__global__ __launch_bounds__(256) void scatter_kernel(const int* __restrict__ lcx,
                                                      int* __restrict__ cur,
                                                      int* __restrict__ sorted)
{
    int f = blockIdx.x * blockDim.x + threadIdx.x;
    if (f < N_FRAGK) {
        const int p = lcx[f];
        const int pos = atomicAdd(&cur[p], 1);
        sorted[pos] = f;
    }
}

// ---------------------------------------------------------------- fused: per-gene GEMM + scans + fragment logdet
// 512 threads, up to 8 ACTIVE cells per block. Thread t owns dims {t, t+512, t+1024}.
__global__ __launch_bounds__(512, 8) void gene_kernel(
    const float* __restrict__ h, const float* __restrict__ spline_w,
    const float* __restrict__ mix_spline, const int* __restrict__ genes_oi,
    const float* __restrict__ coords, const int* __restrict__ off,
    const int* __restrict__ sorted, const int* __restrict__ nact,
    const int* __restrict__ act_list, double* __restrict__ acc)
{
    __shared__ float P[CELLS_PB * CSTRIDE];                 // 48288 B
    __shared__ __align__(16) float hs[N_HIDK][CELLS_PB];    // 1024 B

    const int gl = blockIdx.x >> 4;   // gene-of-interest index
    const int ct = blockIdx.x & 15;   // active-cell tile
    const int na = nact[gl];
    int nv = na - ct * CELLS_PB;
    if (nv <= 0) return;              // uniform: whole block exits (before any barrier)
    if (nv > CELLS_PB) nv = CELLS_PB;

    const int g  = genes_oi[gl];
    const int t  = threadIdx.x;
    const int lane = t & 63;
    const int w = t >> 6;
    const int* al = act_list + gl * N_CELLSK + ct * CELLS_PB;

    if (t < N_HIDK * CELLS_PB) {
        const int c = t & (CELLS_PB - 1), i = t >> 3;
        const int cell = al[c < nv ? c : 0];
        hs[i][c] = h[cell * N_HIDK + i];
    }
    __syncthreads();

    const float* swg  = spline_w + (size_t)g * (N_HIDK * N_SPL);
    const float* mixg = mix_spline + (size_t)g * N_SPL;

    // ---- GEMM: dims d0=t, d1=t+512, d2=t+1024 (d2 masked for t>=475) ----
    {
        const int d0 = t;
        const int d1 = t + 512;
        const bool has2 = (t < N_SPL - 1024);
        const int d2 = has2 ? (t + 1024) : 1024;

        float a0[CELLS_PB], a1[CELLS_PB], a2[CELLS_PB];
        {
            const float m0 = mixg[d0], m1 = mixg[d1], m2 = mixg[d2];
            #pragma unroll
            for (int c = 0; c < CELLS_PB; ++c) { a0[c] = m0; a1[c] = m1; a2[c] = m2; }
        }
        const float* bp = swg;
        #pragma unroll 4
        for (int i = 0; i < N_HIDK; ++i) {
            const float b0 = bp[d0];
            const float b1 = bp[d1];
            const float b2 = bp[d2];
            bp += N_SPL;
            const float4 hA = *(const float4*)&hs[i][0];
            const float4 hB = *(const float4*)&hs[i][4];
            #define STEP(hv,c) a0[c]=fmaf(hv,b0,a0[c]); a1[c]=fmaf(hv,b1,a1[c]); a2[c]=fmaf(hv,b2,a2[c]);
            STEP(hA.x, 0) STEP(hA.y, 1) STEP(hA.z, 2) STEP(hA.w, 3)
            STEP(hB.x, 4) STEP(hB.y, 5) STEP(hB.z, 6) STEP(hB.w, 7)
            #undef STEP
        }
        // store: addr = d + 4*[d>=500] + 4*[d>=1000]; exp for d<1000, raw after
        const int s0 = d0 + ((d0 >= N_BINSK) ? 4 : 0);            // d0 in [0,512)
        const int s1 = d1 + 4 + ((d1 >= 2 * N_BINSK) ? 4 : 0);    // d1 in [512,1024)
        const bool e1 = (d1 < 2 * N_BINSK);
        const int s2 = d2 + 8;                                    // d2 in [1024,1499)
        #pragma unroll
        for (int c = 0; c < CELLS_PB; ++c) {
            float* Pc = P + c * CSTRIDE;
            Pc[s0] = expf(a0[c]);
            Pc[s1] = e1 ? expf(a1[c]) : a1[c];
            if (has2) Pc[s2] = a2[c];
        }
    }
    __syncthreads();

    // per-cell exclusive prefix scans of exp(uw), exp(uh); slot [500] gets total
    for (int s = w; s < 2 * nv; s += 8) {
        float* Pb = P + (s >> 1) * CSTRIDE + ((s & 1) ? 504 : 0);
        float v[8], pre[8];
        float run = 0.f;
        const int base = lane * 8;
        #pragma unroll
        for (int k = 0; k < 8; ++k) {
            const int i = base + k;
            v[k] = (i < N_BINSK) ? Pb[i] : 0.f;
            pre[k] = run; run += v[k];
        }
        float sv = run;
        #pragma unroll
        for (int o = 1; o < 64; o <<= 1) {
            float tt = __shfl_up(sv, o);
            if (lane >= o) sv += tt;
        }
        const float excl = sv - run;
        #pragma unroll
        for (int k = 0; k < 8; ++k) {
            const int i = base + k;
            if (i <= N_BINSK) Pb[i] = excl + pre[k];
        }
    }
    __syncthreads();

    // fragments: one active (cell, gene) pair per wave
    float contrib = 0.f;
    if (w < nv) {
        const int cell = al[w];
        const int p = cell * N_GOI + gl;
        const int o0 = off[p], o1 = off[p + 1];
        const float* PWc = P + w * CSTRIDE;
        const float* PHc = PWc + 504;
        const float* UDc = PWc + 1008;
        const float rSW = 0.5f / PWc[N_BINSK];
        const float rSH = 0.5f / PHc[N_BINSK];
        for (int k = o0; k < o1; ++k) {
            const int fid = sorted[k];
            #pragma unroll 1
            for (int q = 0; q < 2; ++q) {
                const float val = coords[fid * 2 + q];
                const float y = ((val - WIN_A_F) / AB_F - 0.5f) * 2.0f;
                if (!(y >= -1.0f && y <= 1.0f)) continue;   // wave-uniform
                const float yc = y;

                int best = 0;
                for (int j = lane + 1; j <= N_BINSK; j += 64) {
                    const float chv = (j == N_BINSK) ? 1.0f
                                    : 2.0f * (0.001f * (float)j + PHc[j] * rSH) - 1.0f;
                    if (chv <= yc) best = j;
                }
                #pragma unroll
                for (int o = 32; o; o >>= 1) best = max(best, __shfl_xor(best, o));
                const int idx = min(best, N_BINSK - 1);

                const float ch_k  = (idx == 0) ? -1.0f
                                  : 2.0f * (0.001f * (float)idx + PHc[idx] * rSH) - 1.0f;
                const float ch_k1 = (idx == N_BINSK - 1) ? 1.0f
                                  : 2.0f * (0.001f * (float)(idx + 1) + PHc[idx + 1] * rSH) - 1.0f;
                const float h_k = ch_k1 - ch_k;

                const float cw_k  = (idx == 0) ? -1.0f
                                  : 2.0f * (0.001f * (float)idx + PWc[idx] * rSW) - 1.0f;
                const float cw_k1 = (idx == N_BINSK - 1) ? 1.0f
                                  : 2.0f * (0.001f * (float)(idx + 1) + PWc[idx + 1] * rSW) - 1.0f;
                const float w_k = cw_k1 - cw_k;

                const float d_k  = (idx == 0)           ? 1.0f : 0.001f + log1pf(expf(UDc[idx - 1]));
                const float d_k1 = (idx == N_BINSK - 1) ? 1.0f : 0.001f + log1pf(expf(UDc[idx]));

                const float delta = h_k / w_k;
                const float s2 = d_k + d_k1 - 2.0f * delta;
                const float dy = yc - ch_k;
                const float qa = dy * s2 + h_k * (delta - d_k);
                const float qb = h_k * d_k - dy * s2;
                const float qc = -delta * dy;
                const float disc = qb * qb - 4.0f * qa * qc;
                const float root = 2.0f * qc / (-qb - sqrtf(disc));
                const float th1m = root * (1.0f - root);
                const float den = delta + s2 * th1m;
                const float num = delta * delta *
                    (d_k1 * root * root + 2.0f * delta * th1m + d_k * (1.0f - root) * (1.0f - root));
                const float lad = logf(num) - 2.0f * logf(den);
                contrib -= lad;
            }
        }
    }
    if (lane == 0)
        atomicAdd(&acc[((blockIdx.x << 3) | w) & 127], (double)contrib);
}

// ---------------------------------------------------------------- Poisson counts term
__global__ __launch_bounds__(256) void ll_counts_kernel(
    const float* __restrict__ h, const float* __restrict__ rho_w,
    const float* __restrict__ rho_bias, const float* __restrict__ libsize,
    const int* __restrict__ genes_oi, const int* __restrict__ cells_oi,
    const int* __restrict__ counts, double* __restrict__ acc)
{
    int i = blockIdx.x * blockDim.x + threadIdx.x;
    float v = 0.f;
    if (i < N_PAIR) {
        const int c = i / N_GOI;
        const int gl = i - c * N_GOI;
        const int g = genes_oi[gl];
        float rho = 0.f;
        #pragma unroll
        for (int j = 0; j < N_HIDK; ++j)
            rho = fmaf(h[c * N_HIDK + j], rho_w[g * N_HIDK + j], rho);
        const float rate = rho_bias[g] * expf(rho) * libsize[cells_oi[c]];
        const float cnt = (float)counts[i];
        v = cnt * logf(rate) - rate - lgammaf(cnt + 1.0f);
    }
    #pragma unroll
    for (int o = 32; o; o >>= 1) v += __shfl_xor(v, o);
    if ((threadIdx.x & 63) == 0)
        atomicAdd(&acc[128 + (((blockIdx.x << 2) | (threadIdx.x >> 6)) & 63)], (double)v);
}

// ---------------------------------------------------------------- finalize (one wave)
__global__ __launch_bounds__(64) void final_kernel(const double* __restrict__ acc,
                                                   float* __restrict__ out)
{
    const int lane = threadIdx.x;
    double s = acc[lane] + acc[lane + 64] + acc[lane + 128];
    #pragma unroll
    for (int o = 32; o; o >>= 1) s += __shfl_down(s, o);
    if (lane == 0) {
        const double c0 = (double)(2 * N_FRAGK) * (log(0.5) - log((double)AB_F));
        out[0] = (float)(-(s + c0));
    }
}

// ---------------------------------------------------------------- launch
extern "C" void kernel_launch(void* const* d_in, const int* in_sizes, int n_in,
                              void* d_out, int out_size, void* d_ws, size_t ws_size,
                              hipStream_t stream)
{
    const float* latent   = (const float*)d_in[0];
    const float* coords   = (const float*)d_in[1];
    const float* W1       = (const float*)d_in[2];
    const float* b1       = (const float*)d_in[3];
    const float* g1       = (const float*)d_in[4];
    const float* be1      = (const float*)d_in[5];
    const float* W2       = (const float*)d_in[6];
    const float* b2       = (const float*)d_in[7];
    const float* g2       = (const float*)d_in[8];
    const float* be2      = (const float*)d_in[9];
    const float* spline_w = (const float*)d_in[10];
    const float* rho_w    = (const float*)d_in[11];
    const float* mix      = (const float*)d_in[12];
    const float* rho_bias = (const float*)d_in[13];
    const float* libsize  = (const float*)d_in[14];
    const int* genes_oi   = (const int*)d_in[15];
    const int* cells_oi   = (const int*)d_in[16];
    const int* lcx        = (const int*)d_in[17];

    char* ws = (char*)d_ws;
    int*    hist     = (int*)(ws + WS_HIST);
    double* acc      = (double*)(ws + WS_ACC);
    int*    nact     = (int*)(ws + WS_NACT);
    float*  h_ws     = (float*)(ws + WS_H);
    int*    off      = (int*)(ws + WS_OFF);
    int*    cur      = (int*)(ws + WS_CUR);
    int*    sorted   = (int*)(ws + WS_SORT);
    int*    act_list = (int*)(ws + WS_ACT);

    hipMemsetAsync(d_ws, 0, WS_ZERO, stream);   // hist + acc + nact

    hipLaunchKernelGGL(mlp_hist_kernel, dim3(HIST_BLOCKS + 1), dim3(256), 0, stream,
                       latent, W1, b1, g1, be1, W2, b2, g2, be2, h_ws, lcx, hist);
    hipLaunchKernelGGL(scan_kernel, dim3(1), dim3(1024), 0, stream,
                       hist, off, cur, nact, act_list);
    hipLaunchKernelGGL(scatter_kernel, dim3((N_FRAGK + 255) / 256), dim3(256), 0, stream,
                       lcx, cur, sorted);
    hipLaunchKernelGGL(gene_kernel, dim3(N_GOI * N_TILES), dim3(512), 0, stream,
                       h_ws, spline_w, mix, genes_oi, coords, off, sorted, nact, act_list, acc);
    hipLaunchKernelGGL(ll_counts_kernel, dim3((N_PAIR + 255) / 256), dim3(256), 0, stream,
                       h_ws, rho_w, rho_bias, libsize, genes_oi, cells_oi, hist, acc);
    hipLaunchKernelGGL(final_kernel, dim3(1), dim3(64), 0, stream, acc, (float*)d_out);
}

// Round 6
// 299.704 us; speedup vs baseline: 1.3875x; 1.3875x over previous
//
#include <hip/hip_runtime.h>
#include <math.h>

#define N_BINSK  500
#define N_SPL    1499
#define N_CELLSK 128
#define N_GOI    300
#define N_HIDK   32
#define N_LATK   64
#define N_FRAGK  50000
#define N_PAIR   (N_CELLSK * N_GOI)
#define WIN_A_F  (-10000.0f)
#define AB_F     (20000.0f)

#define CELLS_PB 8
#define N_TILES  (N_CELLSK / CELLS_PB)    // 16
#define CSTRIDE  1012   // per-cell floats in P: PW@0 (501 used), PH@504 (501 used)

// ---- workspace layout (bytes) ----
#define WS_HIST  0                                   // int[38400]   @0
#define WS_ACC   (N_PAIR * 4)                        // double[128]  @153600
#define WS_H     (WS_ACC + 128 * 8)                  // float[128*32]@154624
#define WS_OFF   (WS_H + N_CELLSK * N_HIDK * 4)      // int[38401]   @171008
#define WS_CUR   (WS_OFF + (N_PAIR + 1) * 4)         // int[38400]   @324612
#define WS_SORT  (WS_CUR + N_PAIR * 4)               // int[50000]   @478212
#define WS_ZERO  (WS_H)                              // memset hist + acc

#define HIST_BLOCKS 196   // 196*256 = 50176 >= 50000; block 196 runs the MLP

// ---------------------------------------------------------------- MLP (block HIST_BLOCKS) + histogram
__global__ __launch_bounds__(256) void mlp_hist_kernel(
    const float* __restrict__ latent, const float* __restrict__ W1, const float* __restrict__ b1,
    const float* __restrict__ g1, const float* __restrict__ be1,
    const float* __restrict__ W2, const float* __restrict__ b2,
    const float* __restrict__ g2, const float* __restrict__ be2,
    float* __restrict__ h_out, const int* __restrict__ lcx, int* __restrict__ hist)
{
    if (blockIdx.x < HIST_BLOCKS) {
        const int f = blockIdx.x * 256 + threadIdx.x;
        if (f < N_FRAGK) atomicAdd(&hist[lcx[f]], 1);
        return;
    }
    __shared__ float A[N_CELLSK][N_HIDK + 1];
    __shared__ float mean_s[N_HIDK], rstd_s[N_HIDK];
    const int c = threadIdx.x;
    const bool act = (c < N_CELLSK);

    float x[N_LATK];
    if (act) {
        #pragma unroll
        for (int i = 0; i < N_LATK; ++i) x[i] = latent[c * N_LATK + i];
        for (int j = 0; j < N_HIDK; ++j) {
            float a = b1[j];
            #pragma unroll
            for (int i = 0; i < N_LATK; ++i) a = fmaf(x[i], W1[i * N_HIDK + j], a);
            A[c][j] = fmaxf(a, 0.0f);
        }
    }
    __syncthreads();
    if (c < N_HIDK) {
        float m = 0.f;
        for (int i = 0; i < N_CELLSK; ++i) m += A[i][c];
        m *= (1.0f / N_CELLSK);
        float v = 0.f;
        for (int i = 0; i < N_CELLSK; ++i) { float d = A[i][c] - m; v += d * d; }
        v *= (1.0f / N_CELLSK);
        mean_s[c] = m;
        rstd_s[c] = rsqrtf(v + 1e-5f);
    }
    __syncthreads();
    float hb[N_HIDK];
    if (act) {
        #pragma unroll
        for (int j = 0; j < N_HIDK; ++j)
            hb[j] = (A[c][j] - mean_s[j]) * rstd_s[j] * g1[j] + be1[j];
    }
    __syncthreads();
    if (act) {
        for (int j = 0; j < N_HIDK; ++j) {
            float a = b2[j];
            #pragma unroll
            for (int i = 0; i < N_HIDK; ++i) a = fmaf(hb[i], W2[i * N_HIDK + j], a);
            A[c][j] = fmaxf(a, 0.0f);
        }
    }
    __syncthreads();
    if (c < N_HIDK) {
        float m = 0.f;
        for (int i = 0; i < N_CELLSK; ++i) m += A[i][c];
        m *= (1.0f / N_CELLSK);
        float v = 0.f;
        for (int i = 0; i < N_CELLSK; ++i) { float d = A[i][c] - m; v += d * d; }
        v *= (1.0f / N_CELLSK);
        mean_s[c] = m;
        rstd_s[c] = rsqrtf(v + 1e-5f);
    }
    __syncthreads();
    if (act) {
        #pragma unroll
        for (int j = 0; j < N_HIDK; ++j)
            h_out[c * N_HIDK + j] = (A[c][j] - mean_s[j]) * rstd_s[j] * g2[j] + be2[j];
    }
}

// ---------------------------------------------------------------- exclusive scan of hist -> off, cur
__global__ __launch_bounds__(1024) void scan_kernel(const int* __restrict__ hist,
                                                    int* __restrict__ off,
                                                    int* __restrict__ cur)
{
    __shared__ int wsum[16];
    const int t = threadIdx.x, lane = t & 63, w = t >> 6;
    const int base = t * 38;
    int loc[38];
    int run = 0;
    #pragma unroll
    for (int k = 0; k < 38; ++k) {
        const int i = base + k;
        const int v = (i < N_PAIR) ? hist[i] : 0;
        loc[k] = run; run += v;
    }
    int s = run;
    #pragma unroll
    for (int o = 1; o < 64; o <<= 1) {
        int tt = __shfl_up(s, o);
        if (lane >= o) s += tt;
    }
    if (lane == 63) wsum[w] = s;
    __syncthreads();
    if (t == 0) {
        int r = 0;
        #pragma unroll
        for (int j = 0; j < 16; ++j) { const int x = wsum[j]; wsum[j] = r; r += x; }
    }
    __syncthreads();
    const int ex = wsum[w] + (s - run);
    #pragma unroll
    for (int k = 0; k < 38; ++k) {
        const int i = base + k;
        if (i < N_PAIR) { off[i] = ex + loc[k]; cur[i] = ex + loc[k]; }
    }
    if (t == 1023) off[N_PAIR] = ex + run;
}

// ---------------------------------------------------------------- scatter fragments sorted by pair
__global__ __launch_bounds__(256) void scatter_kernel(const int* __restrict__ lcx,
                                                      int* __restrict__ cur,
                                                      int* __restrict__ sorted)
{
    int f = blockIdx.x * blockDim.x + threadIdx.x;
    if (f < N_FRAGK) {
        const int p = lcx[f];
        const int pos = atomicAdd(&cur[p], 1);
        sorted[pos] = f;
    }
}

// ---------------------------------------------------------------- fused: per-gene uw/uh GEMM + scans + fragment logdet + Poisson
// 512 threads, 8 cells per block. Thread t<500 owns dims {2t, 2t+1} (dwordx2 loads).
// ud is NOT precomputed: recomputed per-coordinate (2 columns, 64-lane split dot).
__global__ __launch_bounds__(512, 8) void gene_kernel(
    const float* __restrict__ h, const float* __restrict__ spline_w,
    const float* __restrict__ mix_spline, const int* __restrict__ genes_oi,
    const float* __restrict__ coords, const int* __restrict__ off,
    const int* __restrict__ sorted, const int* __restrict__ hist,
    const float* __restrict__ rho_w, const float* __restrict__ rho_bias,
    const float* __restrict__ libsize, const int* __restrict__ cells_oi,
    double* __restrict__ acc)
{
    __shared__ float P[CELLS_PB * CSTRIDE];                 // 32384 B
    __shared__ __align__(16) float hs[N_HIDK][CELLS_PB];    // 1024 B

    const int gl = blockIdx.x >> 4;   // gene-of-interest index
    const int ct = blockIdx.x & 15;   // 8-cell tile
    const int g  = genes_oi[gl];
    const int t  = threadIdx.x;
    const int lane = t & 63;
    const int w = t >> 6;

    if (t < N_HIDK * CELLS_PB) {
        const int c = t & (CELLS_PB - 1), i = t >> 3;
        hs[i][c] = h[(ct * CELLS_PB + c) * N_HIDK + i];
    }
    __syncthreads();

    const float* swg  = spline_w + (size_t)g * (N_HIDK * N_SPL);
    const float* mixg = mix_spline + (size_t)g * N_SPL;

    // ---- GEMM over uw/uh dims only (d < 1000) ----
    if (t < 500) {
        const int d0 = 2 * t;             // even, in [0, 998]
        const float m0 = mixg[d0], m1 = mixg[d0 + 1];
        float a0[CELLS_PB], a1[CELLS_PB];
        #pragma unroll
        for (int c = 0; c < CELLS_PB; ++c) { a0[c] = m0; a1[c] = m1; }

        const float* bp = swg + d0;
        #pragma unroll 4
        for (int i = 0; i < N_HIDK; ++i) {
            const float b0 = bp[0];
            const float b1 = bp[1];
            bp += N_SPL;
            const float4 hA = *(const float4*)&hs[i][0];
            const float4 hB = *(const float4*)&hs[i][4];
            #define STEP(hv,c) a0[c]=fmaf(hv,b0,a0[c]); a1[c]=fmaf(hv,b1,a1[c]);
            STEP(hA.x, 0) STEP(hA.y, 1) STEP(hA.z, 2) STEP(hA.w, 3)
            STEP(hB.x, 4) STEP(hB.y, 5) STEP(hB.z, 6) STEP(hB.w, 7)
            #undef STEP
        }
        const int s0 = d0 + ((d0 >= N_BINSK) ? 4 : 0);   // both dims same side (d0 even)
        #pragma unroll
        for (int c = 0; c < CELLS_PB; ++c) {
            float* Pc = P + c * CSTRIDE;
            *(float2*)&Pc[s0] = make_float2(expf(a0[c]), expf(a1[c]));
        }
    }
    __syncthreads();

    // per-cell exclusive prefix scans of exp(uw), exp(uh); slot [500] gets total
    for (int s = w; s < 2 * CELLS_PB; s += 8) {
        float* Pb = P + (s >> 1) * CSTRIDE + ((s & 1) ? 504 : 0);
        float v[8], pre[8];
        float run = 0.f;
        const int base = lane * 8;
        #pragma unroll
        for (int k = 0; k < 8; ++k) {
            const int i = base + k;
            v[k] = (i < N_BINSK) ? Pb[i] : 0.f;
            pre[k] = run; run += v[k];
        }
        float sv = run;
        #pragma unroll
        for (int o = 1; o < 64; o <<= 1) {
            float tt = __shfl_up(sv, o);
            if (lane >= o) sv += tt;
        }
        const float excl = sv - run;
        #pragma unroll
        for (int k = 0; k < 8; ++k) {
            const int i = base + k;
            if (i <= N_BINSK) Pb[i] = excl + pre[k];
        }
    }
    __syncthreads();

    // ---- fragments: one (cell, gene) pair per wave ----
    float contrib = 0.f;
    const int cl = w;
    const int cell = ct * CELLS_PB + cl;
    const int p = cell * N_GOI + gl;
    {
        const int o0 = off[p], o1 = off[p + 1];
        if (o0 < o1) {
            const float* PWc = P + cl * CSTRIDE;
            const float* PHc = PWc + 504;
            const float rSW = 0.5f / PWc[N_BINSK];
            const float rSH = 0.5f / PHc[N_BINSK];
            const float hcol = hs[lane & 31][cl];     // my h element for the ud dots
            for (int k = o0; k < o1; ++k) {
                const int fid = sorted[k];
                const float2 cxy = ((const float2*)coords)[fid];
                #pragma unroll 1
                for (int q = 0; q < 2; ++q) {
                    const float val = q ? cxy.y : cxy.x;
                    const float y = ((val - WIN_A_F) / AB_F - 0.5f) * 2.0f;
                    if (!(y >= -1.0f && y <= 1.0f)) continue;   // wave-uniform
                    const float yc = y;

                    int best = 0;
                    for (int j = lane + 1; j <= N_BINSK; j += 64) {
                        const float chv = (j == N_BINSK) ? 1.0f
                                        : 2.0f * (0.001f * (float)j + PHc[j] * rSH) - 1.0f;
                        if (chv <= yc) best = j;
                    }
                    #pragma unroll
                    for (int o = 32; o; o >>= 1) best = max(best, __shfl_xor(best, o));
                    const int idx = min(best, N_BINSK - 1);

                    // on-demand ud: lanes<32 -> column idx-1, lanes>=32 -> column idx
                    const int cA = max(1000 + idx - 1, 1000);
                    const int cB = min(1000 + idx, 1498);
                    float part = hcol * swg[(lane & 31) * N_SPL + ((lane < 32) ? cA : cB)];
                    #pragma unroll
                    for (int o = 16; o; o >>= 1) part += __shfl_xor(part, o);
                    const float udA = __shfl(part, 0)  + mixg[cA];
                    const float udB = __shfl(part, 32) + mixg[cB];
                    const float d_k  = (idx == 0)           ? 1.0f : 0.001f + log1pf(expf(udA));
                    const float d_k1 = (idx == N_BINSK - 1) ? 1.0f : 0.001f + log1pf(expf(udB));

                    const float ch_k  = (idx == 0) ? -1.0f
                                      : 2.0f * (0.001f * (float)idx + PHc[idx] * rSH) - 1.0f;
                    const float ch_k1 = (idx == N_BINSK - 1) ? 1.0f
                                      : 2.0f * (0.001f * (float)(idx + 1) + PHc[idx + 1] * rSH) - 1.0f;
                    const float h_k = ch_k1 - ch_k;

                    const float cw_k  = (idx == 0) ? -1.0f
                                      : 2.0f * (0.001f * (float)idx + PWc[idx] * rSW) - 1.0f;
                    const float cw_k1 = (idx == N_BINSK - 1) ? 1.0f
                                      : 2.0f * (0.001f * (float)(idx + 1) + PWc[idx + 1] * rSW) - 1.0f;
                    const float w_k = cw_k1 - cw_k;

                    const float delta = h_k / w_k;
                    const float s2 = d_k + d_k1 - 2.0f * delta;
                    const float dy = yc - ch_k;
                    const float qa = dy * s2 + h_k * (delta - d_k);
                    const float qb = h_k * d_k - dy * s2;
                    const float qc = -delta * dy;
                    const float disc = qb * qb - 4.0f * qa * qc;
                    const float root = 2.0f * qc / (-qb - sqrtf(disc));
                    const float th1m = root * (1.0f - root);
                    const float den = delta + s2 * th1m;
                    const float num = delta * delta *
                        (d_k1 * root * root + 2.0f * delta * th1m + d_k * (1.0f - root) * (1.0f - root));
                    const float lad = logf(num) - 2.0f * logf(den);
                    contrib -= lad;
                }
            }
        }
    }

    // ---- Poisson counts term for this wave's pair (covers ALL pairs incl. empty) ----
    {
        float part = (lane < 32) ? hs[lane][cl] * rho_w[g * N_HIDK + lane] : 0.f;
        #pragma unroll
        for (int o = 16; o; o >>= 1) part += __shfl_xor(part, o);
        const float rho = __shfl(part, 0);
        const float rate = rho_bias[g] * expf(rho) * libsize[cells_oi[cell]];
        const float cnt = (float)hist[p];
        contrib += cnt * logf(rate) - rate - lgammaf(cnt + 1.0f);
    }

    if (lane == 0)
        atomicAdd(&acc[((blockIdx.x << 3) | w) & 127], (double)contrib);
}

// ---------------------------------------------------------------- finalize (one wave)
__global__ __launch_bounds__(64) void final_kernel(const double* __restrict__ acc,
                                                   float* __restrict__ out)
{
    const int lane = threadIdx.x;
    double s = acc[lane] + acc[lane + 64];
    #pragma unroll
    for (int o = 32; o; o >>= 1) s += __shfl_down(s, o);
    if (lane == 0) {
        const double c0 = (double)(2 * N_FRAGK) * (log(0.5) - log((double)AB_F));
        out[0] = (float)(-(s + c0));
    }
}

// ---------------------------------------------------------------- launch
extern "C" void kernel_launch(void* const* d_in, const int* in_sizes, int n_in,
                              void* d_out, int out_size, void* d_ws, size_t ws_size,
                              hipStream_t stream)
{
    const float* latent   = (const float*)d_in[0];
    const float* coords   = (const float*)d_in[1];
    const float* W1       = (const float*)d_in[2];
    const float* b1       = (const float*)d_in[3];
    const float* g1       = (const float*)d_in[4];
    const float* be1      = (const float*)d_in[5];
    const float* W2       = (const float*)d_in[6];
    const float* b2       = (const float*)d_in[7];
    const float* g2       = (const float*)d_in[8];
    const float* be2      = (const float*)d_in[9];
    const float* spline_w = (const float*)d_in[10];
    const float* rho_w    = (const float*)d_in[11];
    const float* mix      = (const float*)d_in[12];
    const float* rho_bias = (const float*)d_in[13];
    const float* libsize  = (const float*)d_in[14];
    const int* genes_oi   = (const int*)d_in[15];
    const int* cells_oi   = (const int*)d_in[16];
    const int* lcx        = (const int*)d_in[17];

    char* ws = (char*)d_ws;
    int*    hist   = (int*)(ws + WS_HIST);
    double* acc    = (double*)(ws + WS_ACC);
    float*  h_ws   = (float*)(ws + WS_H);
    int*    off    = (int*)(ws + WS_OFF);
    int*    cur    = (int*)(ws + WS_CUR);
    int*    sorted = (int*)(ws + WS_SORT);

    hipMemsetAsync(d_ws, 0, WS_ZERO, stream);   // hist + acc

    hipLaunchKernelGGL(mlp_hist_kernel, dim3(HIST_BLOCKS + 1), dim3(256), 0, stream,
                       latent, W1, b1, g1, be1, W2, b2, g2, be2, h_ws, lcx, hist);
    hipLaunchKernelGGL(scan_kernel, dim3(1), dim3(1024), 0, stream, hist, off, cur);
    hipLaunchKernelGGL(scatter_kernel, dim3((N_FRAGK + 255) / 256), dim3(256), 0, stream,
                       lcx, cur, sorted);
    hipLaunchKernelGGL(gene_kernel, dim3(N_GOI * N_TILES), dim3(512), 0, stream,
                       h_ws, spline_w, mix, genes_oi, coords, off, sorted,
                       hist, rho_w, rho_bias, libsize, cells_oi, acc);
    hipLaunchKernelGGL(final_kernel, dim3(1), dim3(64), 0, stream, acc, (float*)d_out);
}

// Round 7
// 281.999 us; speedup vs baseline: 1.4746x; 1.0628x over previous
//
#include <hip/hip_runtime.h>
#include <math.h>

#define N_BINSK  500
#define N_SPL    1499
#define N_CELLSK 128
#define N_GOI    300
#define N_HIDK   32
#define N_LATK   64
#define N_FRAGK  50000
#define N_PAIR   (N_CELLSK * N_GOI)
#define WIN_A_F  (-10000.0f)
#define AB_F     (20000.0f)

#define CELLS_PB 8
#define N_TILES  (N_CELLSK / CELLS_PB)    // 16
#define CSTRIDE  1012   // per-cell floats in P: PW@0 (501 used), PH@504 (501 used)
#define DPAD     1008   // padded uw/uh dim count for bf16 B (63 MFMA tiles of 16)

// ---- workspace layout (bytes) ----
#define WS_HIST  0                                   // int[38400]   @0
#define WS_ACC   (N_PAIR * 4)                        // double[128]  @153600
#define WS_H     (WS_ACC + 128 * 8)                  // float[128*32]@154624
#define WS_OFF   (WS_H + N_CELLSK * N_HIDK * 4)      // int[38401]   @171008
#define WS_CUR   (WS_OFF + (N_PAIR + 1) * 4)         // int[38400]   @324612
#define WS_SORT  (WS_CUR + N_PAIR * 4)               // int[50000]   @478212
#define WS_HBF   678224                              // ushort[128*32] (16B aligned)
#define WS_SWGT  (WS_HBF + N_CELLSK * N_HIDK * 2)    // ushort[300*1008*32] = 19.35 MB
#define WS_ZERO  (WS_H)                              // memset hist + acc

#define HIST_BLOCKS 196   // 196*256 = 50176 >= 50000; block 196 runs the MLP

typedef __attribute__((ext_vector_type(8))) short bf16x8;
typedef __attribute__((ext_vector_type(4))) float f32x4;

__device__ __forceinline__ unsigned short f2bf(float f)
{
    union { float f; unsigned u; } c; c.f = f;
    return (unsigned short)((c.u + 0x7FFF + ((c.u >> 16) & 1)) >> 16);
}

// ---------------------------------------------------------------- prep: spline_w[genes_oi] uw/uh -> bf16 [gl][dim][hid]
__global__ __launch_bounds__(256) void prep_kernel(
    const float* __restrict__ spline_w, const int* __restrict__ genes_oi,
    unsigned short* __restrict__ swgt)
{
    __shared__ float Ls[N_HIDK][65];
    const int gl = blockIdx.x >> 4;     // 300 genes
    const int chunk = blockIdx.x & 15;  // 16 chunks x 64 dims = 1024 >= 1008
    const int g = genes_oi[gl];
    const int t = threadIdx.x;
    const int dl = t & 63, h0 = t >> 6;
    const int dbase = chunk * 64;

    const float* src = spline_w + (size_t)g * (N_HIDK * N_SPL);
    #pragma unroll
    for (int p = 0; p < 8; ++p) {
        const int hid = h0 + p * 4;
        Ls[hid][dl] = src[(size_t)hid * N_SPL + dbase + dl];   // dbase+dl <= 1023 < 1499
    }
    __syncthreads();

    const int dim = dbase + (t >> 2);
    if (dim < DPAD) {
        const int hseg = (t & 3) * 8;
        unsigned short out[8];
        #pragma unroll
        for (int j = 0; j < 8; ++j) out[j] = f2bf(Ls[hseg + j][t >> 2]);
        *(uint4*)(swgt + ((size_t)(gl * DPAD + dim) * N_HIDK + hseg)) = *(const uint4*)out;
    }
}

// ---------------------------------------------------------------- MLP (block HIST_BLOCKS) + histogram
__global__ __launch_bounds__(256) void mlp_hist_kernel(
    const float* __restrict__ latent, const float* __restrict__ W1, const float* __restrict__ b1,
    const float* __restrict__ g1, const float* __restrict__ be1,
    const float* __restrict__ W2, const float* __restrict__ b2,
    const float* __restrict__ g2, const float* __restrict__ be2,
    float* __restrict__ h_out, unsigned short* __restrict__ h_bf,
    const int* __restrict__ lcx, int* __restrict__ hist)
{
    if (blockIdx.x < HIST_BLOCKS) {
        const int f = blockIdx.x * 256 + threadIdx.x;
        if (f < N_FRAGK) atomicAdd(&hist[lcx[f]], 1);
        return;
    }
    __shared__ float A[N_CELLSK][N_HIDK + 1];
    __shared__ float mean_s[N_HIDK], rstd_s[N_HIDK];
    const int c = threadIdx.x;
    const bool act = (c < N_CELLSK);

    float x[N_LATK];
    if (act) {
        #pragma unroll
        for (int i = 0; i < N_LATK; ++i) x[i] = latent[c * N_LATK + i];
        for (int j = 0; j < N_HIDK; ++j) {
            float a = b1[j];
            #pragma unroll
            for (int i = 0; i < N_LATK; ++i) a = fmaf(x[i], W1[i * N_HIDK + j], a);
            A[c][j] = fmaxf(a, 0.0f);
        }
    }
    __syncthreads();
    if (c < N_HIDK) {
        float m = 0.f;
        for (int i = 0; i < N_CELLSK; ++i) m += A[i][c];
        m *= (1.0f / N_CELLSK);
        float v = 0.f;
        for (int i = 0; i < N_CELLSK; ++i) { float d = A[i][c] - m; v += d * d; }
        v *= (1.0f / N_CELLSK);
        mean_s[c] = m;
        rstd_s[c] = rsqrtf(v + 1e-5f);
    }
    __syncthreads();
    float hb[N_HIDK];
    if (act) {
        #pragma unroll
        for (int j = 0; j < N_HIDK; ++j)
            hb[j] = (A[c][j] - mean_s[j]) * rstd_s[j] * g1[j] + be1[j];
    }
    __syncthreads();
    if (act) {
        for (int j = 0; j < N_HIDK; ++j) {
            float a = b2[j];
            #pragma unroll
            for (int i = 0; i < N_HIDK; ++i) a = fmaf(hb[i], W2[i * N_HIDK + j], a);
            A[c][j] = fmaxf(a, 0.0f);
        }
    }
    __syncthreads();
    if (c < N_HIDK) {
        float m = 0.f;
        for (int i = 0; i < N_CELLSK; ++i) m += A[i][c];
        m *= (1.0f / N_CELLSK);
        float v = 0.f;
        for (int i = 0; i < N_CELLSK; ++i) { float d = A[i][c] - m; v += d * d; }
        v *= (1.0f / N_CELLSK);
        mean_s[c] = m;
        rstd_s[c] = rsqrtf(v + 1e-5f);
    }
    __syncthreads();
    if (act) {
        #pragma unroll
        for (int j = 0; j < N_HIDK; ++j) {
            const float v = (A[c][j] - mean_s[j]) * rstd_s[j] * g2[j] + be2[j];
            h_out[c * N_HIDK + j] = v;
            h_bf[c * N_HIDK + j] = f2bf(v);
        }
    }
}

// ---------------------------------------------------------------- exclusive scan of hist -> off, cur
__global__ __launch_bounds__(1024) void scan_kernel(const int* __restrict__ hist,
                                                    int* __restrict__ off,
                                                    int* __restrict__ cur)
{
    __shared__ int wsum[16];
    const int t = threadIdx.x, lane = t & 63, w = t >> 6;
    const int base = t * 38;
    int loc[38];
    int run = 0;
    #pragma unroll
    for (int k = 0; k < 38; ++k) {
        const int i = base + k;
        const int v = (i < N_PAIR) ? hist[i] : 0;
        loc[k] = run; run += v;
    }
    int s = run;
    #pragma unroll
    for (int o = 1; o < 64; o <<= 1) {
        int tt = __shfl_up(s, o);
        if (lane >= o) s += tt;
    }
    if (lane == 63) wsum[w] = s;
    __syncthreads();
    if (t == 0) {
        int r = 0;
        #pragma unroll
        for (int j = 0; j < 16; ++j) { const int x = wsum[j]; wsum[j] = r; r += x; }
    }
    __syncthreads();
    const int ex = wsum[w] + (s - run);
    #pragma unroll
    for (int k = 0; k < 38; ++k) {
        const int i = base + k;
        if (i < N_PAIR) { off[i] = ex + loc[k]; cur[i] = ex + loc[k]; }
    }
    if (t == 1023) off[N_PAIR] = ex + run;
}

// ---------------------------------------------------------------- scatter fragments sorted by pair
__global__ __launch_bounds__(256) void scatter_kernel(const int* __restrict__ lcx,
                                                      int* __restrict__ cur,
                                                      int* __restrict__ sorted)
{
    int f = blockIdx.x * blockDim.x + threadIdx.x;
    if (f < N_FRAGK) {
        const int p = lcx[f];
        const int pos = atomicAdd(&cur[p], 1);
        sorted[pos] = f;
    }
}

// ---------------------------------------------------------------- fused: MFMA GEMM + scans + fragment logdet + Poisson
__global__ __launch_bounds__(512, 8) void gene_kernel(
    const float* __restrict__ h, const unsigned short* __restrict__ h_bf,
    const unsigned short* __restrict__ swgt,
    const float* __restrict__ spline_w, const float* __restrict__ mix_spline,
    const int* __restrict__ genes_oi, const float* __restrict__ coords,
    const int* __restrict__ off, const int* __restrict__ sorted,
    const int* __restrict__ hist, const float* __restrict__ rho_w,
    const float* __restrict__ rho_bias, const float* __restrict__ libsize,
    const int* __restrict__ cells_oi, double* __restrict__ acc)
{
    __shared__ float P[CELLS_PB * CSTRIDE];   // 32384 B

    const int gl = blockIdx.x >> 4;   // gene-of-interest index
    const int ct = blockIdx.x & 15;   // 8-cell tile
    const int g  = genes_oi[gl];
    const int t  = threadIdx.x;
    const int lane = t & 63;
    const int w = t >> 6;

    const float* swg  = spline_w + (size_t)g * (N_HIDK * N_SPL);
    const float* mixg = mix_spline + (size_t)g * N_SPL;

    // ---- GEMM via MFMA: D[cell 16pad][dim 16] tiles, K=32 in one mfma ----
    {
        const int koff = (lane >> 4) * 8;
        const int arow = ct * CELLS_PB + ((lane & 15) & 7);   // rows 8..15 duplicate 0..7
        const bf16x8 afrag = *(const bf16x8*)(h_bf + arow * N_HIDK + koff);
        const int dcol = lane & 15;
        #pragma unroll 1
        for (int tile = w; tile < 63; tile += 8) {
            const int d = tile * 16 + dcol;
            const bf16x8 bfrag = *(const bf16x8*)(swgt + ((size_t)(gl * DPAD + d) * N_HIDK + koff));
            const float m = mixg[min(d, 999)];
            f32x4 acc4 = {m, m, m, m};
            acc4 = __builtin_amdgcn_mfma_f32_16x16x32_bf16(afrag, bfrag, acc4, 0, 0, 0);
            if (lane < 32 && d < 1000) {
                const int s = d + ((d >= N_BINSK) ? 4 : 0);
                #pragma unroll
                for (int r = 0; r < 4; ++r)
                    P[((lane >> 4) * 4 + r) * CSTRIDE + s] = expf(acc4[r]);
            }
        }
    }
    __syncthreads();

    // per-cell exclusive prefix scans of exp(uw), exp(uh); slot [500] gets total
    for (int s = w; s < 2 * CELLS_PB; s += 8) {
        float* Pb = P + (s >> 1) * CSTRIDE + ((s & 1) ? 504 : 0);
        const int base = lane * 8;
        float v[8], pre[8];
        if (lane < 62) {
            *(float4*)&v[0] = *(const float4*)&Pb[base];
            *(float4*)&v[4] = *(const float4*)&Pb[base + 4];
        } else if (lane == 62) {
            *(float4*)&v[0] = *(const float4*)&Pb[base];
            v[4] = v[5] = v[6] = v[7] = 0.f;    // elems 500..503 unused
        } else {
            #pragma unroll
            for (int k = 0; k < 8; ++k) v[k] = 0.f;
        }
        float run = 0.f;
        #pragma unroll
        for (int k = 0; k < 8; ++k) { pre[k] = run; run += v[k]; }
        float sv = run;
        #pragma unroll
        for (int o = 1; o < 64; o <<= 1) {
            float tt = __shfl_up(sv, o);
            if (lane >= o) sv += tt;
        }
        const float excl = sv - run;
        #pragma unroll
        for (int k = 0; k < 8; ++k) pre[k] += excl;
        if (lane < 63) {                        // lane62 writes [496..503]: [500]=total, rest benign
            *(float4*)&Pb[base]     = *(const float4*)&pre[0];
            *(float4*)&Pb[base + 4] = *(const float4*)&pre[4];
        }
    }
    __syncthreads();

    // ---- fragments: one (cell, gene) pair per wave ----
    float contrib = 0.f;
    const int cl = w;
    const int cell = ct * CELLS_PB + cl;
    const int p = cell * N_GOI + gl;
    {
        const int o0 = off[p], o1 = off[p + 1];
        if (o0 < o1) {
            const float* PWc = P + cl * CSTRIDE;
            const float* PHc = PWc + 504;
            const float rSW = 0.5f / PWc[N_BINSK];
            const float rSH = 0.5f / PHc[N_BINSK];
            const float hcol = h[cell * N_HIDK + (lane & 31)];   // for ud dots
            for (int k = o0; k < o1; ++k) {
                const int fid = sorted[k];
                const float2 cxy = ((const float2*)coords)[fid];
                #pragma unroll 1
                for (int q = 0; q < 2; ++q) {
                    const float val = q ? cxy.y : cxy.x;
                    const float y = ((val - WIN_A_F) / AB_F - 0.5f) * 2.0f;
                    if (!(y >= -1.0f && y <= 1.0f)) continue;   // wave-uniform
                    const float yc = y;

                    int best = 0;
                    for (int j = lane + 1; j <= N_BINSK; j += 64) {
                        const float chv = (j == N_BINSK) ? 1.0f
                                        : 2.0f * (0.001f * (float)j + PHc[j] * rSH) - 1.0f;
                        if (chv <= yc) best = j;
                    }
                    #pragma unroll
                    for (int o = 32; o; o >>= 1) best = max(best, __shfl_xor(best, o));
                    const int idx = min(best, N_BINSK - 1);

                    // on-demand ud: lanes<32 -> column idx-1, lanes>=32 -> column idx
                    const int cA = max(1000 + idx - 1, 1000);
                    const int cB = min(1000 + idx, 1498);
                    float part = hcol * swg[(lane & 31) * N_SPL + ((lane < 32) ? cA : cB)];
                    #pragma unroll
                    for (int o = 16; o; o >>= 1) part += __shfl_xor(part, o);
                    const float udA = __shfl(part, 0)  + mixg[cA];
                    const float udB = __shfl(part, 32) + mixg[cB];
                    const float d_k  = (idx == 0)           ? 1.0f : 0.001f + log1pf(expf(udA));
                    const float d_k1 = (idx == N_BINSK - 1) ? 1.0f : 0.001f + log1pf(expf(udB));

                    const float ch_k  = (idx == 0) ? -1.0f
                                      : 2.0f * (0.001f * (float)idx + PHc[idx] * rSH) - 1.0f;
                    const float ch_k1 = (idx == N_BINSK - 1) ? 1.0f
                                      : 2.0f * (0.001f * (float)(idx + 1) + PHc[idx + 1] * rSH) - 1.0f;
                    const float h_k = ch_k1 - ch_k;

                    const float cw_k  = (idx == 0) ? -1.0f
                                      : 2.0f * (0.001f * (float)idx + PWc[idx] * rSW) - 1.0f;
                    const float cw_k1 = (idx == N_BINSK - 1) ? 1.0f
                                      : 2.0f * (0.001f * (float)(idx + 1) + PWc[idx + 1] * rSW) - 1.0f;
                    const float w_k = cw_k1 - cw_k;

                    const float delta = h_k / w_k;
                    const float s2 = d_k + d_k1 - 2.0f * delta;
                    const float dy = yc - ch_k;
                    const float qa = dy * s2 + h_k * (delta - d_k);
                    const float qb = h_k * d_k - dy * s2;
                    const float qc = -delta * dy;
                    const float disc = qb * qb - 4.0f * qa * qc;
                    const float root = 2.0f * qc / (-qb - sqrtf(disc));
                    const float th1m = root * (1.0f - root);
                    const float den = delta + s2 * th1m;
                    const float num = delta * delta *
                        (d_k1 * root * root + 2.0f * delta * th1m + d_k * (1.0f - root) * (1.0f - root));
                    const float lad = logf(num) - 2.0f * logf(den);
                    contrib -= lad;
                }
            }
        }
    }

    // ---- Poisson counts term for this wave's pair (covers ALL pairs incl. empty) ----
    {
        float part = (lane < 32) ? h[cell * N_HIDK + lane] * rho_w[g * N_HIDK + lane] : 0.f;
        #pragma unroll
        for (int o = 16; o; o >>= 1) part += __shfl_xor(part, o);
        const float rho = __shfl(part, 0);
        const float rate = rho_bias[g] * expf(rho) * libsize[cells_oi[cell]];
        const float cnt = (float)hist[p];
        contrib += cnt * logf(rate) - rate - lgammaf(cnt + 1.0f);
    }

    if (lane == 0)
        atomicAdd(&acc[((blockIdx.x << 3) | w) & 127], (double)contrib);
}

// ---------------------------------------------------------------- finalize (one wave)
__global__ __launch_bounds__(64) void final_kernel(const double* __restrict__ acc,
                                                   float* __restrict__ out)
{
    const int lane = threadIdx.x;
    double s = acc[lane] + acc[lane + 64];
    #pragma unroll
    for (int o = 32; o; o >>= 1) s += __shfl_down(s, o);
    if (lane == 0) {
        const double c0 = (double)(2 * N_FRAGK) * (log(0.5) - log((double)AB_F));
        out[0] = (float)(-(s + c0));
    }
}

// ---------------------------------------------------------------- launch
extern "C" void kernel_launch(void* const* d_in, const int* in_sizes, int n_in,
                              void* d_out, int out_size, void* d_ws, size_t ws_size,
                              hipStream_t stream)
{
    const float* latent   = (const float*)d_in[0];
    const float* coords   = (const float*)d_in[1];
    const float* W1       = (const float*)d_in[2];
    const float* b1       = (const float*)d_in[3];
    const float* g1       = (const float*)d_in[4];
    const float* be1      = (const float*)d_in[5];
    const float* W2       = (const float*)d_in[6];
    const float* b2       = (const float*)d_in[7];
    const float* g2       = (const float*)d_in[8];
    const float* be2      = (const float*)d_in[9];
    const float* spline_w = (const float*)d_in[10];
    const float* rho_w    = (const float*)d_in[11];
    const float* mix      = (const float*)d_in[12];
    const float* rho_bias = (const float*)d_in[13];
    const float* libsize  = (const float*)d_in[14];
    const int* genes_oi   = (const int*)d_in[15];
    const int* cells_oi   = (const int*)d_in[16];
    const int* lcx        = (const int*)d_in[17];

    char* ws = (char*)d_ws;
    int*            hist   = (int*)(ws + WS_HIST);
    double*         acc    = (double*)(ws + WS_ACC);
    float*          h_ws   = (float*)(ws + WS_H);
    int*            off    = (int*)(ws + WS_OFF);
    int*            cur    = (int*)(ws + WS_CUR);
    int*            sorted = (int*)(ws + WS_SORT);
    unsigned short* h_bf   = (unsigned short*)(ws + WS_HBF);
    unsigned short* swgt   = (unsigned short*)(ws + WS_SWGT);

    hipMemsetAsync(d_ws, 0, WS_ZERO, stream);   // hist + acc

    hipLaunchKernelGGL(prep_kernel, dim3(N_GOI * 16), dim3(256), 0, stream,
                       spline_w, genes_oi, swgt);
    hipLaunchKernelGGL(mlp_hist_kernel, dim3(HIST_BLOCKS + 1), dim3(256), 0, stream,
                       latent, W1, b1, g1, be1, W2, b2, g2, be2, h_ws, h_bf, lcx, hist);
    hipLaunchKernelGGL(scan_kernel, dim3(1), dim3(1024), 0, stream, hist, off, cur);
    hipLaunchKernelGGL(scatter_kernel, dim3((N_FRAGK + 255) / 256), dim3(256), 0, stream,
                       lcx, cur, sorted);
    hipLaunchKernelGGL(gene_kernel, dim3(N_GOI * N_TILES), dim3(512), 0, stream,
                       h_ws, h_bf, swgt, spline_w, mix, genes_oi, coords, off, sorted,
                       hist, rho_w, rho_bias, libsize, cells_oi, acc);
    hipLaunchKernelGGL(final_kernel, dim3(1), dim3(64), 0, stream, acc, (float*)d_out);
}

// Round 8
// 200.534 us; speedup vs baseline: 2.0736x; 1.4062x over previous
//
#include <hip/hip_runtime.h>
#include <math.h>

#define N_BINSK  500
#define N_SPL    1499
#define N_CELLSK 128
#define N_GOI    300
#define N_HIDK   32
#define N_LATK   64
#define N_FRAGK  50000
#define N_PAIR   (N_CELLSK * N_GOI)
#define WIN_A_F  (-10000.0f)
#define AB_F     (20000.0f)

#define CELLS_PB 8
#define N_TILES  (N_CELLSK / CELLS_PB)    // 16
#define CSTRIDE  1012   // per-cell floats in P: PW@0 (501 used), PH@504 (501 used)
#define DPAD     1008   // padded uw/uh dim count for bf16 B (63 MFMA tiles of 16)

// ---- workspace layout (bytes) ----
#define WS_HIST  0                                   // int[38400]   @0
#define WS_ACC   (N_PAIR * 4)                        // double[128]  @153600
#define WS_H     (WS_ACC + 128 * 8)                  // float[128*32]@154624
#define WS_OFF   (WS_H + N_CELLSK * N_HIDK * 4)      // int[38401]   @171008
#define WS_CUR   (WS_OFF + (N_PAIR + 1) * 4)         // int[38400]   @324612
#define WS_SORT  (WS_CUR + N_PAIR * 4)               // int[50000]   @478212
#define WS_HBF   678224                              // ushort[128*32] (16B aligned)
#define WS_SWGT  (WS_HBF + N_CELLSK * N_HIDK * 2)    // ushort[300*1008*32] = 19.35 MB
#define WS_ZERO  (WS_H)                              // memset hist + acc

#define HIST_BLOCKS 196   // 196*256 = 50176 >= 50000; block 196 runs the MLP

typedef __attribute__((ext_vector_type(8))) short bf16x8;
typedef __attribute__((ext_vector_type(4))) float f32x4;

__device__ __forceinline__ unsigned short f2bf(float f)
{
    union { float f; unsigned u; } c; c.f = f;
    return (unsigned short)((c.u + 0x7FFF + ((c.u >> 16) & 1)) >> 16);
}

// ---------------------------------------------------------------- prep: spline_w[genes_oi] uw/uh -> bf16 [gl][dim][hid]
__global__ __launch_bounds__(256) void prep_kernel(
    const float* __restrict__ spline_w, const int* __restrict__ genes_oi,
    unsigned short* __restrict__ swgt)
{
    __shared__ float Ls[N_HIDK][65];
    const int gl = blockIdx.x >> 4;     // 300 genes
    const int chunk = blockIdx.x & 15;  // 16 chunks x 64 dims = 1024 >= 1008
    const int g = genes_oi[gl];
    const int t = threadIdx.x;
    const int dl = t & 63, h0 = t >> 6;
    const int dbase = chunk * 64;

    const float* src = spline_w + (size_t)g * (N_HIDK * N_SPL);
    #pragma unroll
    for (int p = 0; p < 8; ++p) {
        const int hid = h0 + p * 4;
        Ls[hid][dl] = src[(size_t)hid * N_SPL + dbase + dl];   // dbase+dl <= 1023 < 1499
    }
    __syncthreads();

    const int dim = dbase + (t >> 2);
    if (dim < DPAD) {
        const int hseg = (t & 3) * 8;
        unsigned short out[8];
        #pragma unroll
        for (int j = 0; j < 8; ++j) out[j] = f2bf(Ls[hseg + j][t >> 2]);
        *(uint4*)(swgt + ((size_t)(gl * DPAD + dim) * N_HIDK + hseg)) = *(const uint4*)out;
    }
}

// ---------------------------------------------------------------- MLP (block HIST_BLOCKS) + histogram
__global__ __launch_bounds__(256) void mlp_hist_kernel(
    const float* __restrict__ latent, const float* __restrict__ W1, const float* __restrict__ b1,
    const float* __restrict__ g1, const float* __restrict__ be1,
    const float* __restrict__ W2, const float* __restrict__ b2,
    const float* __restrict__ g2, const float* __restrict__ be2,
    float* __restrict__ h_out, unsigned short* __restrict__ h_bf,
    const int* __restrict__ lcx, int* __restrict__ hist)
{
    if (blockIdx.x < HIST_BLOCKS) {
        const int f = blockIdx.x * 256 + threadIdx.x;
        if (f < N_FRAGK) atomicAdd(&hist[lcx[f]], 1);
        return;
    }
    __shared__ float A[N_CELLSK][N_HIDK + 1];
    __shared__ float mean_s[N_HIDK], rstd_s[N_HIDK];
    const int c = threadIdx.x;
    const bool act = (c < N_CELLSK);

    float x[N_LATK];
    if (act) {
        #pragma unroll
        for (int i = 0; i < N_LATK; ++i) x[i] = latent[c * N_LATK + i];
        for (int j = 0; j < N_HIDK; ++j) {
            float a = b1[j];
            #pragma unroll
            for (int i = 0; i < N_LATK; ++i) a = fmaf(x[i], W1[i * N_HIDK + j], a);
            A[c][j] = fmaxf(a, 0.0f);
        }
    }
    __syncthreads();
    if (c < N_HIDK) {
        float m = 0.f;
        for (int i = 0; i < N_CELLSK; ++i) m += A[i][c];
        m *= (1.0f / N_CELLSK);
        float v = 0.f;
        for (int i = 0; i < N_CELLSK; ++i) { float d = A[i][c] - m; v += d * d; }
        v *= (1.0f / N_CELLSK);
        mean_s[c] = m;
        rstd_s[c] = rsqrtf(v + 1e-5f);
    }
    __syncthreads();
    float hb[N_HIDK];
    if (act) {
        #pragma unroll
        for (int j = 0; j < N_HIDK; ++j)
            hb[j] = (A[c][j] - mean_s[j]) * rstd_s[j] * g1[j] + be1[j];
    }
    __syncthreads();
    if (act) {
        for (int j = 0; j < N_HIDK; ++j) {
            float a = b2[j];
            #pragma unroll
            for (int i = 0; i < N_HIDK; ++i) a = fmaf(hb[i], W2[i * N_HIDK + j], a);
            A[c][j] = fmaxf(a, 0.0f);
        }
    }
    __syncthreads();
    if (c < N_HIDK) {
        float m = 0.f;
        for (int i = 0; i < N_CELLSK; ++i) m += A[i][c];
        m *= (1.0f / N_CELLSK);
        float v = 0.f;
        for (int i = 0; i < N_CELLSK; ++i) { float d = A[i][c] - m; v += d * d; }
        v *= (1.0f / N_CELLSK);
        mean_s[c] = m;
        rstd_s[c] = rsqrtf(v + 1e-5f);
    }
    __syncthreads();
    if (act) {
        #pragma unroll
        for (int j = 0; j < N_HIDK; ++j) {
            const float v = (A[c][j] - mean_s[j]) * rstd_s[j] * g2[j] + be2[j];
            h_out[c * N_HIDK + j] = v;
            h_bf[c * N_HIDK + j] = f2bf(v);
        }
    }
}

// ---------------------------------------------------------------- exclusive scan of hist -> off, cur
__global__ __launch_bounds__(1024) void scan_kernel(const int* __restrict__ hist,
                                                    int* __restrict__ off,
                                                    int* __restrict__ cur)
{
    __shared__ int wsum[16];
    const int t = threadIdx.x, lane = t & 63, w = t >> 6;
    const int base = t * 38;
    int loc[38];
    int run = 0;
    #pragma unroll
    for (int k = 0; k < 38; ++k) {
        const int i = base + k;
        const int v = (i < N_PAIR) ? hist[i] : 0;
        loc[k] = run; run += v;
    }
    int s = run;
    #pragma unroll
    for (int o = 1; o < 64; o <<= 1) {
        int tt = __shfl_up(s, o);
        if (lane >= o) s += tt;
    }
    if (lane == 63) wsum[w] = s;
    __syncthreads();
    if (t == 0) {
        int r = 0;
        #pragma unroll
        for (int j = 0; j < 16; ++j) { const int x = wsum[j]; wsum[j] = r; r += x; }
    }
    __syncthreads();
    const int ex = wsum[w] + (s - run);
    #pragma unroll
    for (int k = 0; k < 38; ++k) {
        const int i = base + k;
        if (i < N_PAIR) { off[i] = ex + loc[k]; cur[i] = ex + loc[k]; }
    }
    if (t == 1023) off[N_PAIR] = ex + run;
}

// ---------------------------------------------------------------- scatter fragments sorted by pair
__global__ __launch_bounds__(256) void scatter_kernel(const int* __restrict__ lcx,
                                                      int* __restrict__ cur,
                                                      int* __restrict__ sorted)
{
    int f = blockIdx.x * blockDim.x + threadIdx.x;
    if (f < N_FRAGK) {
        const int p = lcx[f];
        const int pos = atomicAdd(&cur[p], 1);
        sorted[pos] = f;
    }
}

// ---------------------------------------------------------------- fused: MFMA GEMM + scans + per-lane fragment logdet + Poisson
__global__ __launch_bounds__(512, 8) void gene_kernel(
    const float* __restrict__ h, const unsigned short* __restrict__ h_bf,
    const unsigned short* __restrict__ swgt,
    const float* __restrict__ spline_w, const float* __restrict__ mix_spline,
    const int* __restrict__ genes_oi, const float* __restrict__ coords,
    const int* __restrict__ off, const int* __restrict__ sorted,
    const int* __restrict__ hist, const float* __restrict__ rho_w,
    const float* __restrict__ rho_bias, const float* __restrict__ libsize,
    const int* __restrict__ cells_oi, double* __restrict__ acc)
{
    __shared__ float P[CELLS_PB * CSTRIDE];   // 32384 B

    const int gl = blockIdx.x >> 4;   // gene-of-interest index
    const int ct = blockIdx.x & 15;   // 8-cell tile
    const int g  = genes_oi[gl];
    const int t  = threadIdx.x;
    const int lane = t & 63;
    const int w = t >> 6;

    const float* swg  = spline_w + (size_t)g * (N_HIDK * N_SPL);
    const float* mixg = mix_spline + (size_t)g * N_SPL;

    // ---- GEMM via MFMA: D[cell 16pad][dim 16] tiles, K=32 in one mfma ----
    {
        const int koff = (lane >> 4) * 8;
        const int arow = ct * CELLS_PB + ((lane & 15) & 7);   // rows 8..15 duplicate 0..7
        const bf16x8 afrag = *(const bf16x8*)(h_bf + arow * N_HIDK + koff);
        const int dcol = lane & 15;
        #pragma unroll 1
        for (int tile = w; tile < 63; tile += 8) {
            const int d = tile * 16 + dcol;
            const bf16x8 bfrag = *(const bf16x8*)(swgt + ((size_t)(gl * DPAD + d) * N_HIDK + koff));
            const float m = mixg[min(d, 999)];
            f32x4 acc4 = {m, m, m, m};
            acc4 = __builtin_amdgcn_mfma_f32_16x16x32_bf16(afrag, bfrag, acc4, 0, 0, 0);
            if (lane < 32 && d < 1000) {
                const int s = d + ((d >= N_BINSK) ? 4 : 0);
                #pragma unroll
                for (int r = 0; r < 4; ++r)
                    P[((lane >> 4) * 4 + r) * CSTRIDE + s] = expf(acc4[r]);
            }
        }
    }
    __syncthreads();

    // per-cell exclusive prefix scans of exp(uw), exp(uh); slot [500] gets total
    for (int s = w; s < 2 * CELLS_PB; s += 8) {
        float* Pb = P + (s >> 1) * CSTRIDE + ((s & 1) ? 504 : 0);
        const int base = lane * 8;
        float v[8], pre[8];
        if (lane < 62) {
            *(float4*)&v[0] = *(const float4*)&Pb[base];
            *(float4*)&v[4] = *(const float4*)&Pb[base + 4];
        } else if (lane == 62) {
            *(float4*)&v[0] = *(const float4*)&Pb[base];
            v[4] = v[5] = v[6] = v[7] = 0.f;    // elems 500..503 unused
        } else {
            #pragma unroll
            for (int k = 0; k < 8; ++k) v[k] = 0.f;
        }
        float run = 0.f;
        #pragma unroll
        for (int k = 0; k < 8; ++k) { pre[k] = run; run += v[k]; }
        float sv = run;
        #pragma unroll
        for (int o = 1; o < 64; o <<= 1) {
            float tt = __shfl_up(sv, o);
            if (lane >= o) sv += tt;
        }
        const float excl = sv - run;
        #pragma unroll
        for (int k = 0; k < 8; ++k) pre[k] += excl;
        if (lane < 63) {                        // lane62 writes [496..503]: [500]=total, rest benign
            *(float4*)&Pb[base]     = *(const float4*)&pre[0];
            *(float4*)&Pb[base + 4] = *(const float4*)&pre[4];
        }
    }
    __syncthreads();

    // ---- fragments: one pair per wave, one COORD PER LANE (batches of 64) ----
    float contrib = 0.f;
    const int cl = w;
    const int cell = ct * CELLS_PB + cl;
    const int p = cell * N_GOI + gl;
    {
        const int o0 = off[p], o1 = off[p + 1];
        const int ncoord = 2 * (o1 - o0);
        if (ncoord > 0) {
            const float* PWc = P + cl * CSTRIDE;
            const float* PHc = PWc + 504;
            const float rSW = 0.5f / PWc[N_BINSK];
            const float rSH = 0.5f / PHc[N_BINSK];
            const float* hrow = h + cell * N_HIDK;
            #pragma unroll 1
            for (int cbase = 0; cbase < ncoord; cbase += 64) {
                const int ci = cbase + lane;
                bool act = (ci < ncoord);
                float yc = 0.f;
                if (act) {
                    const int fid = sorted[o0 + (ci >> 1)];
                    const float val = coords[fid * 2 + (ci & 1)];
                    yc = ((val - WIN_A_F) / AB_F - 0.5f) * 2.0f;
                    act = (yc >= -1.0f) && (yc <= 1.0f);
                }
                if (act) {
                    // per-lane binary search: largest j in [0,500] with chv(j) <= yc
                    int lo = 0, hi = 500;
                    #pragma unroll 1
                    while (lo < hi) {
                        const int mid = (lo + hi + 1) >> 1;
                        const float chv = (mid == N_BINSK) ? 1.0f
                                        : 2.0f * (0.001f * (float)mid + PHc[mid] * rSH) - 1.0f;
                        if (chv <= yc) lo = mid; else hi = mid - 1;
                    }
                    const int idx = min(lo, N_BINSK - 1);

                    // per-lane on-demand ud dot: columns (999+clamp) and +1
                    const int bcol = 999 + min(max(idx, 1), 498);
                    float dA = 0.f, dB = 0.f;
                    #pragma unroll 8
                    for (int i = 0; i < N_HIDK; ++i) {
                        const float hv = hrow[i];                       // wave-uniform
                        const float* cp = swg + (size_t)i * N_SPL + bcol;
                        dA = fmaf(hv, cp[0], dA);
                        dB = fmaf(hv, cp[1], dB);
                    }
                    float udA = 0.f, udB = 0.f;
                    if (idx == 0)                 udB = dA + mixg[1000];
                    else if (idx == N_BINSK - 1)  udA = dB + mixg[1498];
                    else { udA = dA + mixg[bcol]; udB = dB + mixg[bcol + 1]; }
                    const float d_k  = (idx == 0)           ? 1.0f : 0.001f + log1pf(expf(udA));
                    const float d_k1 = (idx == N_BINSK - 1) ? 1.0f : 0.001f + log1pf(expf(udB));

                    const float ch_k  = (idx == 0) ? -1.0f
                                      : 2.0f * (0.001f * (float)idx + PHc[idx] * rSH) - 1.0f;
                    const float ch_k1 = (idx == N_BINSK - 1) ? 1.0f
                                      : 2.0f * (0.001f * (float)(idx + 1) + PHc[idx + 1] * rSH) - 1.0f;
                    const float h_k = ch_k1 - ch_k;

                    const float cw_k  = (idx == 0) ? -1.0f
                                      : 2.0f * (0.001f * (float)idx + PWc[idx] * rSW) - 1.0f;
                    const float cw_k1 = (idx == N_BINSK - 1) ? 1.0f
                                      : 2.0f * (0.001f * (float)(idx + 1) + PWc[idx + 1] * rSW) - 1.0f;
                    const float w_k = cw_k1 - cw_k;

                    const float delta = h_k / w_k;
                    const float s2 = d_k + d_k1 - 2.0f * delta;
                    const float dy = yc - ch_k;
                    const float qa = dy * s2 + h_k * (delta - d_k);
                    const float qb = h_k * d_k - dy * s2;
                    const float qc = -delta * dy;
                    const float disc = qb * qb - 4.0f * qa * qc;
                    const float root = 2.0f * qc / (-qb - sqrtf(disc));
                    const float th1m = root * (1.0f - root);
                    const float den = delta + s2 * th1m;
                    const float num = delta * delta *
                        (d_k1 * root * root + 2.0f * delta * th1m + d_k * (1.0f - root) * (1.0f - root));
                    const float lad = logf(num) - 2.0f * logf(den);
                    contrib -= lad;
                }
            }
        }
    }
    // wave-reduce per-lane contribs
    #pragma unroll
    for (int o = 32; o; o >>= 1) contrib += __shfl_xor(contrib, o);

    // ---- Poisson counts term for this wave's pair (covers ALL pairs incl. empty) ----
    {
        float part = (lane < 32) ? h[cell * N_HIDK + lane] * rho_w[g * N_HIDK + lane] : 0.f;
        #pragma unroll
        for (int o = 16; o; o >>= 1) part += __shfl_xor(part, o);
        const float rho = __shfl(part, 0);
        const float rate = rho_bias[g] * expf(rho) * libsize[cells_oi[cell]];
        const float cnt = (float)hist[p];
        contrib += cnt * logf(rate) - rate - lgammaf(cnt + 1.0f);
    }

    if (lane == 0)
        atomicAdd(&acc[((blockIdx.x << 3) | w) & 127], (double)contrib);
}

// ---------------------------------------------------------------- finalize (one wave)
__global__ __launch_bounds__(64) void final_kernel(const double* __restrict__ acc,
                                                   float* __restrict__ out)
{
    const int lane = threadIdx.x;
    double s = acc[lane] + acc[lane + 64];
    #pragma unroll
    for (int o = 32; o; o >>= 1) s += __shfl_down(s, o);
    if (lane == 0) {
        const double c0 = (double)(2 * N_FRAGK) * (log(0.5) - log((double)AB_F));
        out[0] = (float)(-(s + c0));
    }
}

// ---------------------------------------------------------------- launch
extern "C" void kernel_launch(void* const* d_in, const int* in_sizes, int n_in,
                              void* d_out, int out_size, void* d_ws, size_t ws_size,
                              hipStream_t stream)
{
    const float* latent   = (const float*)d_in[0];
    const float* coords   = (const float*)d_in[1];
    const float* W1       = (const float*)d_in[2];
    const float* b1       = (const float*)d_in[3];
    const float* g1       = (const float*)d_in[4];
    const float* be1      = (const float*)d_in[5];
    const float* W2       = (const float*)d_in[6];
    const float* b2       = (const float*)d_in[7];
    const float* g2       = (const float*)d_in[8];
    const float* be2      = (const float*)d_in[9];
    const float* spline_w = (const float*)d_in[10];
    const float* rho_w    = (const float*)d_in[11];
    const float* mix      = (const float*)d_in[12];
    const float* rho_bias = (const float*)d_in[13];
    const float* libsize  = (const float*)d_in[14];
    const int* genes_oi   = (const int*)d_in[15];
    const int* cells_oi   = (const int*)d_in[16];
    const int* lcx        = (const int*)d_in[17];

    char* ws = (char*)d_ws;
    int*            hist   = (int*)(ws + WS_HIST);
    double*         acc    = (double*)(ws + WS_ACC);
    float*          h_ws   = (float*)(ws + WS_H);
    int*            off    = (int*)(ws + WS_OFF);
    int*            cur    = (int*)(ws + WS_CUR);
    int*            sorted = (int*)(ws + WS_SORT);
    unsigned short* h_bf   = (unsigned short*)(ws + WS_HBF);
    unsigned short* swgt   = (unsigned short*)(ws + WS_SWGT);

    hipMemsetAsync(d_ws, 0, WS_ZERO, stream);   // hist + acc

    hipLaunchKernelGGL(prep_kernel, dim3(N_GOI * 16), dim3(256), 0, stream,
                       spline_w, genes_oi, swgt);
    hipLaunchKernelGGL(mlp_hist_kernel, dim3(HIST_BLOCKS + 1), dim3(256), 0, stream,
                       latent, W1, b1, g1, be1, W2, b2, g2, be2, h_ws, h_bf, lcx, hist);
    hipLaunchKernelGGL(scan_kernel, dim3(1), dim3(1024), 0, stream, hist, off, cur);
    hipLaunchKernelGGL(scatter_kernel, dim3((N_FRAGK + 255) / 256), dim3(256), 0, stream,
                       lcx, cur, sorted);
    hipLaunchKernelGGL(gene_kernel, dim3(N_GOI * N_TILES), dim3(512), 0, stream,
                       h_ws, h_bf, swgt, spline_w, mix, genes_oi, coords, off, sorted,
                       hist, rho_w, rho_bias, libsize, cells_oi, acc);
    hipLaunchKernelGGL(final_kernel, dim3(1), dim3(64), 0, stream, acc, (float*)d_out);
}